// Round 2
// baseline (305.587 us; speedup 1.0000x reference)
//
#include <hip/hip_runtime.h>
#include <stdint.h>

typedef __attribute__((ext_vector_type(8))) short bf16x8;   // 8 bf16 raw bits (4 VGPRs)
typedef __attribute__((ext_vector_type(4))) float f32x4;    // MFMA accumulator / vec load

static __device__ __forceinline__ uint16_t f2bf(float f) {
    uint32_t u;
    __builtin_memcpy(&u, &f, 4);
    return (uint16_t)((u + 0x7FFFu + ((u >> 16) & 1u)) >> 16);   // RNE
}

// ---------------------------------------------------------------------------
// K1: X = (I - A)^-1 B via forward substitution (fp32 in, fp32 out).
// One block, 128 threads; thread d owns column d of X.
// x[s] = (B[s,d] + sum_{t<s} A[s,t] x[t]) / (1 - A[s,s]).
// A staged in LDS (64 KB); A[s][t] reads are wave-uniform -> LDS broadcast.
// ---------------------------------------------------------------------------
__global__ __launch_bounds__(128) void k1_solve(const float* __restrict__ Ag,
                                                const float* __restrict__ Bg,
                                                float* __restrict__ X) {
    __shared__ float As[128 * 128];   // exactly 64 KB
    const int d = threadIdx.x;
    for (int i = 0; i < 128; ++i) As[i * 128 + d] = Ag[i * 128 + d];
    __syncthreads();

    float x[128];
#pragma unroll
    for (int s = 0; s < 128; ++s) {
        const float* Ar = &As[s * 128];
        float a0 = 0.f, a1 = 0.f, a2 = 0.f, a3 = 0.f;
        const int s4 = s & ~3;
#pragma unroll
        for (int t = 0; t < s4; t += 4) {
            a0 += Ar[t + 0] * x[t + 0];
            a1 += Ar[t + 1] * x[t + 1];
            a2 += Ar[t + 2] * x[t + 2];
            a3 += Ar[t + 3] * x[t + 3];
        }
#pragma unroll
        for (int t = s4; t < s; ++t) a0 += Ar[t] * x[t];
        float num = Bg[s * 128 + d] + ((a0 + a1) + (a2 + a3));
        x[s] = num / (1.0f - Ar[s]);
    }
#pragma unroll
    for (int s = 0; s < 128; ++s) X[s * 128 + d] = x[s];   // coalesced
}

// ---------------------------------------------------------------------------
// K2: M[o][d] = sum_s C[o][s] * X[s][d] + D[o][d] (fp32 math), rounded to bf16
// directly in MFMA B-operand fragment order for 16x16x32:
//   B[k=d][n=o]; lane = ((d>>3)&3)*16 + (o&15); j = d&7; frag f = (o>>4)*4 + (d>>5)
//   element index = (f*64 + lane)*8 + j   (each lane: 8 contiguous k, 16 B)
// ---------------------------------------------------------------------------
__global__ __launch_bounds__(128) void k2_makeM(const float* __restrict__ X,
                                                const float* __restrict__ Cg,
                                                const float* __restrict__ Dg,
                                                uint16_t* __restrict__ Mfrag) {
    const int o = blockIdx.x;    // 0..127 output row of M
    const int d = threadIdx.x;   // 0..127 column (k dim of the big GEMM)
    float a0 = 0.f, a1 = 0.f, a2 = 0.f, a3 = 0.f;
#pragma unroll
    for (int s = 0; s < 128; s += 4) {
        a0 += Cg[o * 128 + s + 0] * X[(s + 0) * 128 + d];
        a1 += Cg[o * 128 + s + 1] * X[(s + 1) * 128 + d];
        a2 += Cg[o * 128 + s + 2] * X[(s + 2) * 128 + d];
        a3 += Cg[o * 128 + s + 3] * X[(s + 3) * 128 + d];
    }
    float m = ((a0 + a1) + (a2 + a3)) + Dg[o * 128 + d];

    const int c = o >> 4, n = o & 15;
    const int t = d >> 5, r = d & 31;
    const int half = r >> 3, j = r & 7;
    const int lane = half * 16 + n;
    const int f = c * 4 + t;
    Mfrag[(f * 64 + lane) * 8 + j] = f2bf(m);
}

// ---------------------------------------------------------------------------
// K3: y = u @ M^T.  262144 x 128 rows, K=128, N=128. fp32 u loaded as float4
// pairs, packed to bf16 in-register, bf16 MFMA 16x16x32, fp32 y stores.
// Block = 256 thr (4 waves). M fragments resident in VGPRs (32 frags x 16 B).
// A layout: A[m=lane&15][k=(lane>>4)*8+j]; C/D: col=lane&15, row=(lane>>4)*4+r.
// ---------------------------------------------------------------------------
__global__ __launch_bounds__(256, 2) void k3_gemm(const float* __restrict__ U,
                                                  const uint16_t* __restrict__ Mfrag,
                                                  float* __restrict__ Y) {
    const int lane = threadIdx.x & 63;
    const int wid  = threadIdx.x >> 6;

    // B fragments: load once, reuse for all row tiles (L2-resident 32 KB).
    bf16x8 Bfr[8][4];
#pragma unroll
    for (int c = 0; c < 8; ++c)
#pragma unroll
        for (int t = 0; t < 4; ++t)
            Bfr[c][t] = *reinterpret_cast<const bf16x8*>(Mfrag + ((c * 4 + t) * 64 + lane) * 8);

    const int am = lane & 15;   // A row within tile
    const int kh = lane >> 4;   // k-quad (0..3), 8 contiguous k each

#pragma unroll 1
    for (int it = 0; it < 4; ++it) {
        const int rowbase = blockIdx.x * 256 + it * 64 + wid * 16;

        const float* up = U + (size_t)(rowbase + am) * 128 + kh * 8;
        bf16x8 Afr[4];
#pragma unroll
        for (int t = 0; t < 4; ++t) {
            f32x4 lo = *reinterpret_cast<const f32x4*>(up + t * 32);
            f32x4 hi = *reinterpret_cast<const f32x4*>(up + t * 32 + 4);
            bf16x8 a;
#pragma unroll
            for (int j = 0; j < 4; ++j) {
                a[j]     = (short)f2bf(lo[j]);
                a[4 + j] = (short)f2bf(hi[j]);
            }
            Afr[t] = a;
        }

        f32x4 acc[8] = {};
#pragma unroll
        for (int c = 0; c < 8; ++c)
#pragma unroll
            for (int t = 0; t < 4; ++t)
                acc[c] = __builtin_amdgcn_mfma_f32_16x16x32_bf16(Afr[t], Bfr[c][t], acc[c], 0, 0, 0);

        float* yp = Y + (size_t)(rowbase + kh * 4) * 128 + am;
#pragma unroll
        for (int c = 0; c < 8; ++c)
#pragma unroll
            for (int r = 0; r < 4; ++r)
                yp[(size_t)r * 128 + c * 16] = acc[c][r];
    }
}

// ---------------------------------------------------------------------------
extern "C" void kernel_launch(void* const* d_in, const int* in_sizes, int n_in,
                              void* d_out, int out_size, void* d_ws, size_t ws_size,
                              hipStream_t stream) {
    const float* u = (const float*)d_in[0];   // [32, 8192, 128] fp32
    const float* A = (const float*)d_in[1];   // [128, 128] fp32, lower-tri
    const float* B = (const float*)d_in[2];   // [128, 128] fp32
    const float* C = (const float*)d_in[3];   // [128, 128] fp32
    const float* D = (const float*)d_in[4];   // [128, 128] fp32

    float*    X     = (float*)d_ws;                          // 64 KB fp32
    uint16_t* Mfrag = (uint16_t*)((char*)d_ws + 65536);      // 32 KB bf16 frag order
    float*    Y     = (float*)d_out;                         // [32*8192, 128] fp32

    hipLaunchKernelGGL(k1_solve, dim3(1),    dim3(128), 0, stream, A, B, X);
    hipLaunchKernelGGL(k2_makeM, dim3(128),  dim3(128), 0, stream, X, C, D, Mfrag);
    hipLaunchKernelGGL(k3_gemm,  dim3(1024), dim3(256), 0, stream, u, Mfrag, Y);
}

// Round 3
// 302.628 us; speedup vs baseline: 1.0098x; 1.0098x over previous
//
#include <hip/hip_runtime.h>
#include <stdint.h>

typedef __attribute__((ext_vector_type(8))) short bf16x8;   // 8 bf16 raw bits (4 VGPRs)
typedef __attribute__((ext_vector_type(4))) float f32x4;    // MFMA accumulator / vec load

static __device__ __forceinline__ uint16_t f2bf(float f) {
    uint32_t u;
    __builtin_memcpy(&u, &f, 4);
    return (uint16_t)((u + 0x7FFFu + ((u >> 16) & 1u)) >> 16);   // RNE
}

// ---------------------------------------------------------------------------
// K1: X = (I - A)^-1 B via forward substitution (fp32 in, fp32 out).
// One block, 128 threads; thread d owns column d of X.
// x[s] = (B[s,d] + sum_{t<s} A[s,t] x[t]) / (1 - A[s,s]).
// __launch_bounds__(128, 1): single-resident-block kernel — allow the full
// VGPR budget so x[128] stays in registers (round-2 theory: it spilled).
// A row reads vectorized to ds_read_b128.
// ---------------------------------------------------------------------------
__global__ __launch_bounds__(128, 1) void k1_solve(const float* __restrict__ Ag,
                                                   const float* __restrict__ Bg,
                                                   float* __restrict__ X) {
    __shared__ float As[128 * 128];   // 64 KB
    const int d = threadIdx.x;
    for (int i = 0; i < 128; ++i) As[i * 128 + d] = Ag[i * 128 + d];
    __syncthreads();

    float x[128];
#pragma unroll
    for (int s = 0; s < 128; ++s) {
        const float* Ar = &As[s * 128];
        float a0 = 0.f, a1 = 0.f, a2 = 0.f, a3 = 0.f;
        const int s4 = s & ~3;
#pragma unroll
        for (int t = 0; t < s4; t += 4) {
            f32x4 av = *reinterpret_cast<const f32x4*>(Ar + t);   // ds_read_b128
            a0 += av[0] * x[t + 0];
            a1 += av[1] * x[t + 1];
            a2 += av[2] * x[t + 2];
            a3 += av[3] * x[t + 3];
        }
#pragma unroll
        for (int t = s4; t < s; ++t) a0 += Ar[t] * x[t];
        float num = Bg[s * 128 + d] + ((a0 + a1) + (a2 + a3));
        x[s] = num / (1.0f - Ar[s]);
    }
#pragma unroll
    for (int s = 0; s < 128; ++s) X[s * 128 + d] = x[s];   // coalesced
}

// ---------------------------------------------------------------------------
// K2: M[o][d] = sum_s C[o][s] * X[s][d] + D[o][d] (fp32 math), rounded to bf16
// directly in MFMA B-operand fragment order for 16x16x32:
//   B[k=d][n=o]; lane = ((d>>3)&3)*16 + (o&15); j = d&7; frag f = (o>>4)*4 + (d>>5)
//   element index = (f*64 + lane)*8 + j   (each lane: 8 contiguous k, 16 B)
// ---------------------------------------------------------------------------
__global__ __launch_bounds__(128) void k2_makeM(const float* __restrict__ X,
                                                const float* __restrict__ Cg,
                                                const float* __restrict__ Dg,
                                                uint16_t* __restrict__ Mfrag) {
    const int o = blockIdx.x;    // 0..127 output row of M
    const int d = threadIdx.x;   // 0..127 column (k dim of the big GEMM)
    float a0 = 0.f, a1 = 0.f, a2 = 0.f, a3 = 0.f;
#pragma unroll
    for (int s = 0; s < 128; s += 4) {
        a0 += Cg[o * 128 + s + 0] * X[(s + 0) * 128 + d];
        a1 += Cg[o * 128 + s + 1] * X[(s + 1) * 128 + d];
        a2 += Cg[o * 128 + s + 2] * X[(s + 2) * 128 + d];
        a3 += Cg[o * 128 + s + 3] * X[(s + 3) * 128 + d];
    }
    float m = ((a0 + a1) + (a2 + a3)) + Dg[o * 128 + d];

    const int c = o >> 4, n = o & 15;
    const int t = d >> 5, r = d & 31;
    const int half = r >> 3, j = r & 7;
    const int lane = half * 16 + n;
    const int f = c * 4 + t;
    Mfrag[(f * 64 + lane) * 8 + j] = f2bf(m);
}

// ---------------------------------------------------------------------------
// K3: y = u @ M^T.  262144 rows, K=128, N=128. One 16-row tile per WAVE,
// grid 4096 x 256 thr (4 waves = 64 rows/block). M staged once per block in
// LDS (32 KB); B-frags via ds_read_b128 inside the c-loop. u loaded fp32,
// packed to bf16 in-register; y stored fp32. Wave retires after its stores
// (no iter loop -> no store/acc WAR serialization, latency hidden by TLP).
// A layout: A[m=lane&15][k=(lane>>4)*8+j]; C/D: col=lane&15, row=(lane>>4)*4+r.
// ---------------------------------------------------------------------------
__global__ __launch_bounds__(256, 4) void k3_gemm(const float* __restrict__ U,
                                                  const uint16_t* __restrict__ Mfrag,
                                                  float* __restrict__ Y) {
    __shared__ uint16_t Msh[16384];   // 32 KB: 32 frags x 64 lanes x 8 bf16
    {
        const uint4* src = reinterpret_cast<const uint4*>(Mfrag);
        uint4* dst = reinterpret_cast<uint4*>(Msh);
#pragma unroll
        for (int i = 0; i < 8; ++i)
            dst[threadIdx.x + 256 * i] = src[threadIdx.x + 256 * i];
    }
    __syncthreads();

    const int lane = threadIdx.x & 63;
    const int wid  = threadIdx.x >> 6;
    const int am = lane & 15;   // A row within tile
    const int kh = lane >> 4;   // k-quad (0..3), 8 contiguous k each

    const int rowbase = blockIdx.x * 64 + wid * 16;

    // Load + pack this wave's 16x128 u tile: 8 dwordx4 per lane.
    const float* up = U + (size_t)(rowbase + am) * 128 + kh * 8;
    bf16x8 Afr[4];
#pragma unroll
    for (int t = 0; t < 4; ++t) {
        f32x4 lo = *reinterpret_cast<const f32x4*>(up + t * 32);
        f32x4 hi = *reinterpret_cast<const f32x4*>(up + t * 32 + 4);
        bf16x8 a;
#pragma unroll
        for (int j = 0; j < 4; ++j) {
            a[j]     = (short)f2bf(lo[j]);
            a[4 + j] = (short)f2bf(hi[j]);
        }
        Afr[t] = a;
    }

    f32x4 acc[8] = {};
#pragma unroll
    for (int c = 0; c < 8; ++c) {
#pragma unroll
        for (int t = 0; t < 4; ++t) {
            bf16x8 b = *reinterpret_cast<const bf16x8*>(Msh + ((c * 4 + t) * 64 + lane) * 8);
            acc[c] = __builtin_amdgcn_mfma_f32_16x16x32_bf16(Afr[t], b, acc[c], 0, 0, 0);
        }
    }

    float* yp = Y + (size_t)(rowbase + kh * 4) * 128 + am;
#pragma unroll
    for (int c = 0; c < 8; ++c)
#pragma unroll
        for (int r = 0; r < 4; ++r)
            yp[(size_t)r * 128 + c * 16] = acc[c][r];
}

// ---------------------------------------------------------------------------
extern "C" void kernel_launch(void* const* d_in, const int* in_sizes, int n_in,
                              void* d_out, int out_size, void* d_ws, size_t ws_size,
                              hipStream_t stream) {
    const float* u = (const float*)d_in[0];   // [32, 8192, 128] fp32
    const float* A = (const float*)d_in[1];   // [128, 128] fp32, lower-tri
    const float* B = (const float*)d_in[2];   // [128, 128] fp32
    const float* C = (const float*)d_in[3];   // [128, 128] fp32
    const float* D = (const float*)d_in[4];   // [128, 128] fp32

    float*    X     = (float*)d_ws;                          // 64 KB fp32
    uint16_t* Mfrag = (uint16_t*)((char*)d_ws + 65536);      // 32 KB bf16 frag order
    float*    Y     = (float*)d_out;                         // [32*8192, 128] fp32

    hipLaunchKernelGGL(k1_solve, dim3(1),    dim3(128), 0, stream, A, B, X);
    hipLaunchKernelGGL(k2_makeM, dim3(128),  dim3(128), 0, stream, X, C, D, Mfrag);
    hipLaunchKernelGGL(k3_gemm,  dim3(4096), dim3(256), 0, stream, u, Mfrag, Y);
}